// Round 1
// baseline (623.364 us; speedup 1.0000x reference)
//
#include <hip/hip_runtime.h>

// SpikingNeuronLayer: xlin = x @ W^T + b  -> sequential scan over T with
// leaky integrate, adaptive threshold (unbiased std over H), spike+reset.
//
// Phase 1: fp32 GEMM (M=32768, N=512, K=512) writes xlin into d_out's spike
//          region (same size) -- no workspace needed.
// Phase 2: scan kernel, one wave per batch row, reads xlin in place and
//          overwrites with spikes; writes final mem at the tail of d_out.

#define ALPHA_F 0.95122942450071402f  // float(exp(-1/20)), matches jax f32 promotion

constexpr int Bb = 32, T = 1024, D = 512, Hh = 512;
constexpr int M = Bb * T;  // 32768

// ---------------------------------------------------------------- GEMM ----
#define BM 128
#define BN 128
#define BK 16

__global__ __launch_bounds__(256) void gemm_kernel(
    const float* __restrict__ X,     // [M, K]
    const float* __restrict__ W,     // [N, K]
    const float* __restrict__ bias,  // [N]
    float* __restrict__ out)         // [M, N]
{
  const int K = D, N = Hh;
  const int bn = blockIdx.x;  // 0..3
  const int bm = blockIdx.y;  // 0..255

  __shared__ float As[BK][BM + 4];  // transposed: As[k][m]
  __shared__ float Bs[BK][BN + 4];  // transposed: Bs[k][n]

  const int tid = threadIdx.x;
  const int tm = tid >> 4;    // 0..15
  const int tn = tid & 15;    // 0..15

  float acc[8][8];
#pragma unroll
  for (int i = 0; i < 8; ++i)
#pragma unroll
    for (int j = 0; j < 8; ++j) acc[i][j] = 0.f;

  const int rowA = bm * BM;
  const int rowB = bn * BN;

  for (int k0 = 0; k0 < K; k0 += BK) {
    __syncthreads();
#pragma unroll
    for (int i = 0; i < 2; ++i) {
      const int f = tid * 2 + i;        // 0..511
      const int r = f >> 2;             // 0..127
      const int c4 = (f & 3) << 2;      // 0,4,8,12
      float4 a = *(const float4*)(X + (size_t)(rowA + r) * K + k0 + c4);
      As[c4 + 0][r] = a.x; As[c4 + 1][r] = a.y;
      As[c4 + 2][r] = a.z; As[c4 + 3][r] = a.w;
      float4 w = *(const float4*)(W + (size_t)(rowB + r) * K + k0 + c4);
      Bs[c4 + 0][r] = w.x; Bs[c4 + 1][r] = w.y;
      Bs[c4 + 2][r] = w.z; Bs[c4 + 3][r] = w.w;
    }
    __syncthreads();
#pragma unroll
    for (int k = 0; k < BK; ++k) {
      // split row/col halves so B-reads are 2-way (free) instead of 4-way
      float4 a0 = *(const float4*)&As[k][tm * 4];
      float4 a1 = *(const float4*)&As[k][64 + tm * 4];
      float4 b0 = *(const float4*)&Bs[k][tn * 4];
      float4 b1 = *(const float4*)&Bs[k][64 + tn * 4];
      float av[8] = {a0.x, a0.y, a0.z, a0.w, a1.x, a1.y, a1.z, a1.w};
      float bv[8] = {b0.x, b0.y, b0.z, b0.w, b1.x, b1.y, b1.z, b1.w};
#pragma unroll
      for (int i = 0; i < 8; ++i)
#pragma unroll
        for (int j = 0; j < 8; ++j)
          acc[i][j] = fmaf(av[i], bv[j], acc[i][j]);
    }
  }

  const int c0 = rowB + tn * 4;
  const int c1 = rowB + 64 + tn * 4;
  float4 bb0 = *(const float4*)(bias + c0);
  float4 bb1 = *(const float4*)(bias + c1);
  float bc[8] = {bb0.x, bb0.y, bb0.z, bb0.w, bb1.x, bb1.y, bb1.z, bb1.w};

#pragma unroll
  for (int i = 0; i < 8; ++i) {
    const int r = rowA + ((i < 4) ? (tm * 4 + i) : (64 + tm * 4 + (i - 4)));
    float4 v0, v1;
    v0.x = acc[i][0] + bc[0]; v0.y = acc[i][1] + bc[1];
    v0.z = acc[i][2] + bc[2]; v0.w = acc[i][3] + bc[3];
    v1.x = acc[i][4] + bc[4]; v1.y = acc[i][5] + bc[5];
    v1.z = acc[i][6] + bc[6]; v1.w = acc[i][7] + bc[7];
    *(float4*)(out + (size_t)r * N + c0) = v0;
    *(float4*)(out + (size_t)r * N + c1) = v1;
  }
}

// ---------------------------------------------------------------- scan ----
// One wave (64 lanes) per batch row. Lane handles 8 hidden units:
// h0 = lane*4 .. +3  and  h1 = 256 + lane*4 .. +3  (float4-coalesced).
__global__ __launch_bounds__(64) void scan_kernel(
    float* __restrict__ xs,        // [B,T,H]: in xlin, out spikes (in place)
    const float* __restrict__ ta,  // [H] threshold_adapt
    float* __restrict__ memout)    // [B,H]
{
  const int b = blockIdx.x;
  const int lane = threadIdx.x;
  float* base = xs + (size_t)b * T * Hh;
  const int h0 = lane * 4;
  const int h1 = 256 + lane * 4;

  float4 tav0 = *(const float4*)(ta + h0);
  float4 tav1 = *(const float4*)(ta + h1);
  float tac[8] = {tav0.x, tav0.y, tav0.z, tav0.w,
                  tav1.x, tav1.y, tav1.z, tav1.w};

  float m[8];
#pragma unroll
  for (int i = 0; i < 8; ++i) m[i] = 0.f;

  constexpr int DEPTH = 4;  // prefetch depth (hides HBM latency of xlin reads)
  float4 pa[DEPTH], pb[DEPTH];
#pragma unroll
  for (int u = 0; u < DEPTH; ++u) {
    pa[u] = *(const float4*)(base + (size_t)u * Hh + h0);
    pb[u] = *(const float4*)(base + (size_t)u * Hh + h1);
  }

  for (int t0 = 0; t0 < T; t0 += DEPTH) {
#pragma unroll
    for (int u = 0; u < DEPTH; ++u) {
      const int t = t0 + u;
      const float4 xa = pa[u];
      const float4 xb = pb[u];
      const int tp = t + DEPTH;
      if (tp < T) {  // uniform branch
        pa[u] = *(const float4*)(base + (size_t)tp * Hh + h0);
        pb[u] = *(const float4*)(base + (size_t)tp * Hh + h1);
      }

      const float x[8] = {xa.x, xa.y, xa.z, xa.w, xb.x, xb.y, xb.z, xb.w};
#pragma unroll
      for (int i = 0; i < 8; ++i) m[i] = fmaf(ALPHA_F, m[i], x[i]);

      // per-lane partial sums (pairwise trees)
      float s = ((m[0] + m[1]) + (m[2] + m[3])) +
                ((m[4] + m[5]) + (m[6] + m[7]));
      float q = ((m[0] * m[0] + m[1] * m[1]) + (m[2] * m[2] + m[3] * m[3])) +
                ((m[4] * m[4] + m[5] * m[5]) + (m[6] * m[6] + m[7] * m[7]));

      // 64-lane butterfly reduce (sum + sumsq chains overlap)
#pragma unroll
      for (int off = 1; off < 64; off <<= 1) {
        s += __shfl_xor(s, off, 64);
        q += __shfl_xor(q, off, 64);
      }

      // unbiased variance over H: (sumsq - sum^2/H) / (H-1)
      float var = (q - s * s * (1.0f / Hh)) * (1.0f / (Hh - 1));
      var = fmaxf(var, 0.f);
      const float sd = sqrtf(var);

      float sp[8];
#pragma unroll
      for (int i = 0; i < 8; ++i) {
        const float thr = tac[i] + 0.1f * sd;
        const bool fire = (m[i] >= thr);
        sp[i] = fire ? 1.f : 0.f;
        m[i] = fire ? 0.f : m[i];
      }
      *(float4*)(base + (size_t)t * Hh + h0) =
          make_float4(sp[0], sp[1], sp[2], sp[3]);
      *(float4*)(base + (size_t)t * Hh + h1) =
          make_float4(sp[4], sp[5], sp[6], sp[7]);
    }
  }

  *(float4*)(memout + (size_t)b * Hh + h0) = make_float4(m[0], m[1], m[2], m[3]);
  *(float4*)(memout + (size_t)b * Hh + h1) = make_float4(m[4], m[5], m[6], m[7]);
}

// -------------------------------------------------------------- launch ----
extern "C" void kernel_launch(void* const* d_in, const int* in_sizes, int n_in,
                              void* d_out, int out_size, void* d_ws,
                              size_t ws_size, hipStream_t stream) {
  const float* x    = (const float*)d_in[0];  // [B,T,D]
  const float* W    = (const float*)d_in[1];  // [H,D]
  const float* bias = (const float*)d_in[2];  // [H]
  const float* ta   = (const float*)d_in[3];  // [H]

  float* out    = (float*)d_out;
  float* spikes = out;                          // [B,T,H] (xlin scratch first)
  float* memout = out + (size_t)Bb * T * Hh;    // [B,H]

  dim3 ggrid(Hh / BN, M / BM);  // (4, 256)
  gemm_kernel<<<ggrid, dim3(256), 0, stream>>>(x, W, bias, spikes);
  scan_kernel<<<dim3(Bb), dim3(64), 0, stream>>>(spikes, ta, memout);
}

// Round 2
// 489.205 us; speedup vs baseline: 1.2742x; 1.2742x over previous
//
#include <hip/hip_runtime.h>

// SpikingNeuronLayer: xlin = x @ W^T + b  -> sequential scan over T with
// leaky integrate, adaptive threshold (unbiased std over H), spike+reset.
//
// Phase 1: fp32 GEMM (M=32768, N=512, K=512) writes xlin into d_out's spike
//          region (same size) -- no workspace needed.
// Phase 2: scan kernel, one wave per batch row, latency-bound. R2: DPP-based
//          wave reduction (no LDS round trips) + software-pipelined recurrence
//          (speculative fmaf overlaps the reduce/sqrt chain).

#define ALPHA_F 0.95122942450071402f  // float(exp(-1/20))

constexpr int Bb = 32, T = 1024, D = 512, Hh = 512;
constexpr int M = Bb * T;  // 32768

// ---------------------------------------------------------------- GEMM ----
#define BM 128
#define BN 128
#define BK 16

__global__ __launch_bounds__(256) void gemm_kernel(
    const float* __restrict__ X,     // [M, K]
    const float* __restrict__ W,     // [N, K]
    const float* __restrict__ bias,  // [N]
    float* __restrict__ out)         // [M, N]
{
  const int K = D, N = Hh;
  const int bn = blockIdx.x;  // 0..3
  const int bm = blockIdx.y;  // 0..255

  __shared__ float As[BK][BM + 4];  // transposed: As[k][m]
  __shared__ float Bs[BK][BN + 4];  // transposed: Bs[k][n]

  const int tid = threadIdx.x;
  const int tm = tid >> 4;    // 0..15
  const int tn = tid & 15;    // 0..15

  float acc[8][8];
#pragma unroll
  for (int i = 0; i < 8; ++i)
#pragma unroll
    for (int j = 0; j < 8; ++j) acc[i][j] = 0.f;

  const int rowA = bm * BM;
  const int rowB = bn * BN;

  for (int k0 = 0; k0 < K; k0 += BK) {
    __syncthreads();
#pragma unroll
    for (int i = 0; i < 2; ++i) {
      const int f = tid * 2 + i;        // 0..511
      const int r = f >> 2;             // 0..127
      const int c4 = (f & 3) << 2;      // 0,4,8,12
      float4 a = *(const float4*)(X + (size_t)(rowA + r) * K + k0 + c4);
      As[c4 + 0][r] = a.x; As[c4 + 1][r] = a.y;
      As[c4 + 2][r] = a.z; As[c4 + 3][r] = a.w;
      float4 w = *(const float4*)(W + (size_t)(rowB + r) * K + k0 + c4);
      Bs[c4 + 0][r] = w.x; Bs[c4 + 1][r] = w.y;
      Bs[c4 + 2][r] = w.z; Bs[c4 + 3][r] = w.w;
    }
    __syncthreads();
#pragma unroll
    for (int k = 0; k < BK; ++k) {
      float4 a0 = *(const float4*)&As[k][tm * 4];
      float4 a1 = *(const float4*)&As[k][64 + tm * 4];
      float4 b0 = *(const float4*)&Bs[k][tn * 4];
      float4 b1 = *(const float4*)&Bs[k][64 + tn * 4];
      float av[8] = {a0.x, a0.y, a0.z, a0.w, a1.x, a1.y, a1.z, a1.w};
      float bv[8] = {b0.x, b0.y, b0.z, b0.w, b1.x, b1.y, b1.z, b1.w};
#pragma unroll
      for (int i = 0; i < 8; ++i)
#pragma unroll
        for (int j = 0; j < 8; ++j)
          acc[i][j] = fmaf(av[i], bv[j], acc[i][j]);
    }
  }

  const int c0 = rowB + tn * 4;
  const int c1 = rowB + 64 + tn * 4;
  float4 bb0 = *(const float4*)(bias + c0);
  float4 bb1 = *(const float4*)(bias + c1);
  float bc[8] = {bb0.x, bb0.y, bb0.z, bb0.w, bb1.x, bb1.y, bb1.z, bb1.w};

#pragma unroll
  for (int i = 0; i < 8; ++i) {
    const int r = rowA + ((i < 4) ? (tm * 4 + i) : (64 + tm * 4 + (i - 4)));
    float4 v0, v1;
    v0.x = acc[i][0] + bc[0]; v0.y = acc[i][1] + bc[1];
    v0.z = acc[i][2] + bc[2]; v0.w = acc[i][3] + bc[3];
    v1.x = acc[i][4] + bc[4]; v1.y = acc[i][5] + bc[5];
    v1.z = acc[i][6] + bc[6]; v1.w = acc[i][7] + bc[7];
    *(float4*)(out + (size_t)r * N + c0) = v0;
    *(float4*)(out + (size_t)r * N + c1) = v1;
  }
}

// ---------------------------------------------------------------- scan ----
// DPP wave-64 sum reduction: row_shr 1/2/4/8 within 16-lane rows, then
// row_bcast15 / row_bcast31 fold rows; total lands in lane 63; readlane
// broadcasts it via SGPR. All VALU, no LDS latency on the critical path.
template <int CTRL>
__device__ __forceinline__ float dpp_add(float v) {
  int s = __builtin_amdgcn_update_dpp(0, __builtin_bit_cast(int, v),
                                      CTRL, 0xF, 0xF, true);
  return v + __builtin_bit_cast(float, s);
}

__device__ __forceinline__ float wave_total(float v) {
  v = dpp_add<0x111>(v);  // row_shr:1
  v = dpp_add<0x112>(v);  // row_shr:2
  v = dpp_add<0x114>(v);  // row_shr:4
  v = dpp_add<0x118>(v);  // row_shr:8  -> lane 15 of each row = row sum
  v = dpp_add<0x142>(v);  // row_bcast15
  v = dpp_add<0x143>(v);  // row_bcast31 -> lane 63 = wave sum
  return __builtin_bit_cast(
      float, __builtin_amdgcn_readlane(__builtin_bit_cast(int, v), 63));
}

// One wave (64 lanes) per batch row. Lane handles 8 hidden units:
// h0 = lane*4..+3 and h1 = 256+lane*4..+3 (float4-coalesced).
// Recurrence is software-pipelined: c = fmaf(alpha, mr, x_next) depends only
// on mr (known before the reduction), so it overlaps DPP/sqrt. Selects via
// bool mask + cndmask keep the reset path bitwise-exact (mr = x on fire).
__global__ __launch_bounds__(64) void scan_kernel(
    float* __restrict__ xs,        // [B,T,H]: in xlin, out spikes (in place)
    const float* __restrict__ ta,  // [H] threshold_adapt
    float* __restrict__ memout)    // [B,H]
{
  const int b = blockIdx.x;
  const int lane = threadIdx.x;
  float* base = xs + (size_t)b * (size_t)(T * Hh);
  const int h0 = lane * 4;
  const int h1 = 256 + lane * 4;

  float4 tav0 = *(const float4*)(ta + h0);
  float4 tav1 = *(const float4*)(ta + h1);
  float tac[8] = {tav0.x, tav0.y, tav0.z, tav0.w,
                  tav1.x, tav1.y, tav1.z, tav1.w};

  constexpr int DEPTH = 4;  // prefetch depth
  float4 pa[DEPTH], pb[DEPTH];
#pragma unroll
  for (int u = 0; u < DEPTH; ++u) {
    pa[u] = *(const float4*)(base + (size_t)u * Hh + h0);
    pb[u] = *(const float4*)(base + (size_t)u * Hh + h1);
  }

  // Pipeline state for t=0: mr_0 = x_0 (mem starts at 0).
  float xc[8];  // x_t (carried)
  float c[8];   // speculative alpha*mr_{t-1} + x_t
  {
    const float4 a = pa[0], bq = pb[0];
    xc[0] = a.x; xc[1] = a.y; xc[2] = a.z; xc[3] = a.w;
    xc[4] = bq.x; xc[5] = bq.y; xc[6] = bq.z; xc[7] = bq.w;
  }
#pragma unroll
  for (int i = 0; i < 8; ++i) c[i] = xc[i];
  bool fire[8];
#pragma unroll
  for (int i = 0; i < 8; ++i) fire[i] = false;
  float mr[8];

  for (int t0 = 0; t0 < T; t0 += DEPTH) {
#pragma unroll
    for (int u = 0; u < DEPTH; ++u) {
      const int t = t0 + u;

      // prefetch t+DEPTH into slot u (slot's old value consumed at t-1)
      const int tp = t + DEPTH;
      if (tp < T) {  // uniform
        pa[u] = *(const float4*)(base + (size_t)tp * Hh + h0);
        pb[u] = *(const float4*)(base + (size_t)tp * Hh + h1);
      }

      // 1. resolve current mem: mr = fire_prev ? x_t : alpha*mr_prev + x_t
#pragma unroll
      for (int i = 0; i < 8; ++i) mr[i] = fire[i] ? xc[i] : c[i];

      // 2. per-lane partial sums (pairwise trees)
      float s = ((mr[0] + mr[1]) + (mr[2] + mr[3])) +
                ((mr[4] + mr[5]) + (mr[6] + mr[7]));
      float q = ((mr[0] * mr[0] + mr[1] * mr[1]) +
                 (mr[2] * mr[2] + mr[3] * mr[3])) +
                ((mr[4] * mr[4] + mr[5] * mr[5]) +
                 (mr[6] * mr[6] + mr[7] * mr[7]));

      // 3. speculative next-step update -- independent of the reduction,
      //    overlaps with DPP + sqrt below.
      if (t + 1 < T) {  // uniform
        const float4 na = (u < DEPTH - 1) ? pa[u + 1] : pa[0];
        const float4 nb = (u < DEPTH - 1) ? pb[u + 1] : pb[0];
        xc[0] = na.x; xc[1] = na.y; xc[2] = na.z; xc[3] = na.w;
        xc[4] = nb.x; xc[5] = nb.y; xc[6] = nb.z; xc[7] = nb.w;
#pragma unroll
        for (int i = 0; i < 8; ++i) c[i] = fmaf(ALPHA_F, mr[i], xc[i]);
      }

      // 4. wave reduction + std
      s = wave_total(s);
      q = wave_total(q);
      float var = (q - s * s * (1.0f / Hh)) * (1.0f / (Hh - 1));
      var = fmaxf(var, 0.f);
      const float sd = sqrtf(var);

      // 5. threshold, spike, store
      float sp[8];
#pragma unroll
      for (int i = 0; i < 8; ++i) {
        fire[i] = mr[i] >= fmaf(0.1f, sd, tac[i]);
        sp[i] = fire[i] ? 1.f : 0.f;
      }
      *(float4*)(base + (size_t)t * Hh + h0) =
          make_float4(sp[0], sp[1], sp[2], sp[3]);
      *(float4*)(base + (size_t)t * Hh + h1) =
          make_float4(sp[4], sp[5], sp[6], sp[7]);
    }
  }

  // final mem (post-reset of last step)
  float mf[8];
#pragma unroll
  for (int i = 0; i < 8; ++i) mf[i] = fire[i] ? 0.f : mr[i];
  *(float4*)(memout + (size_t)b * Hh + h0) = make_float4(mf[0], mf[1], mf[2], mf[3]);
  *(float4*)(memout + (size_t)b * Hh + h1) = make_float4(mf[4], mf[5], mf[6], mf[7]);
}

// -------------------------------------------------------------- launch ----
extern "C" void kernel_launch(void* const* d_in, const int* in_sizes, int n_in,
                              void* d_out, int out_size, void* d_ws,
                              size_t ws_size, hipStream_t stream) {
  const float* x    = (const float*)d_in[0];  // [B,T,D]
  const float* W    = (const float*)d_in[1];  // [H,D]
  const float* bias = (const float*)d_in[2];  // [H]
  const float* ta   = (const float*)d_in[3];  // [H]

  float* out    = (float*)d_out;
  float* spikes = out;                          // [B,T,H] (xlin scratch first)
  float* memout = out + (size_t)Bb * T * Hh;    // [B,H]

  dim3 ggrid(Hh / BN, M / BM);  // (4, 256)
  gemm_kernel<<<ggrid, dim3(256), 0, stream>>>(x, W, bias, spikes);
  scan_kernel<<<dim3(Bb), dim3(64), 0, stream>>>(spikes, ta, memout);
}

// Round 3
// 404.218 us; speedup vs baseline: 1.5421x; 1.2103x over previous
//
#include <hip/hip_runtime.h>

// SpikingNeuronLayer fused producer/consumer:
//   blocks 0..31   : scan role, one wave per batch row, spin-waits on per-chunk
//                    progress flags (agent-scope acquire), s_setprio(3).
//   blocks 32..511 : persistent GEMM workers, claim 128x128 tiles chunk-major
//                    via atomic ticket, signal with agent-scope RELEASE add.
// xlin is written into d_out's spike region and overwritten in place by the
// scan. Progress flags + ticket live in d_ws (zeroed each launch by a tiny
// kernel -- deterministic under graph replay).

#define ALPHA_F 0.95122942450071402f  // float(exp(-1/20))

constexpr int Bb = 32, T = 1024, D = 512, Hh = 512;
constexpr int M = Bb * T;               // 32768
constexpr int NSCAN = 32;
constexpr int NGEMM_BLOCKS = 480;
constexpr int NTILES = (M / 128) * (Hh / 128);  // 1024

#define BM 128
#define BN 128
#define BK 16

// ------------------------------------------------------------ DPP reduce ----
template <int CTRL>
__device__ __forceinline__ float dpp_add(float v) {
  int s = __builtin_amdgcn_update_dpp(0, __builtin_bit_cast(int, v),
                                      CTRL, 0xF, 0xF, true);
  return v + __builtin_bit_cast(float, s);
}

// 64-lane sum; result valid in lane 63 only (caller readlanes).
__device__ __forceinline__ float dpp_reduce(float v) {
  v = dpp_add<0x111>(v);  // row_shr:1
  v = dpp_add<0x112>(v);  // row_shr:2
  v = dpp_add<0x114>(v);  // row_shr:4
  v = dpp_add<0x118>(v);  // row_shr:8
  v = dpp_add<0x142>(v);  // row_bcast15
  v = dpp_add<0x143>(v);  // row_bcast31 -> lane 63 = total
  return v;
}

// ------------------------------------------------------------- zero ws ----
__global__ void zero_ws_kernel(unsigned* ws) {
  if (threadIdx.x < 257) ws[threadIdx.x] = 0;  // prog[256] + ticket
}

// ------------------------------------------------------------ fused ----
__global__ __launch_bounds__(256) void fused_kernel(
    const float* __restrict__ X,     // [M, D]
    const float* __restrict__ W,     // [H, D]
    const float* __restrict__ bias,  // [H]
    const float* __restrict__ ta,    // [H]
    float* out,                      // [M, H]: xlin then spikes (in place)
    float* memout,                   // [B, H]
    unsigned* ws)                    // prog[256], ticket
{
  unsigned* prog = ws;
  unsigned* ticket = ws + 256;
  const int tid = threadIdx.x;

  if (blockIdx.x >= NSCAN) {
    // ------------------------------ GEMM role (persistent, ticketed) ------
    __shared__ float As[BK][BM + 4];
    __shared__ float Bs[BK][BN + 4];
    __shared__ unsigned s_g;
    const int tm = tid >> 4;
    const int tn = tid & 15;
    for (;;) {
      __syncthreads();  // protects s_g WAR + As/Bs across tiles
      if (tid == 0)
        s_g = __hip_atomic_fetch_add(ticket, 1u, __ATOMIC_RELAXED,
                                     __HIP_MEMORY_SCOPE_AGENT);
      __syncthreads();
      const unsigned g = s_g;
      if (g >= NTILES) break;  // uniform
      // chunk-major decode: g = c*128 + bt*4 + bn ; bm = bt*8 + c
      const int c  = (int)(g >> 7);
      const int bt = (int)((g & 127u) >> 2);
      const int bn = (int)(g & 3u);
      const int bm = bt * 8 + c;
      const int rowA = bm * BM;
      const int rowB = bn * BN;

      float acc[8][8];
#pragma unroll
      for (int i = 0; i < 8; ++i)
#pragma unroll
        for (int j = 0; j < 8; ++j) acc[i][j] = 0.f;

      for (int k0 = 0; k0 < D; k0 += BK) {
        __syncthreads();
#pragma unroll
        for (int i = 0; i < 2; ++i) {
          const int f = tid * 2 + i;    // 0..511
          const int r = f >> 2;         // 0..127
          const int c4 = (f & 3) << 2;  // 0,4,8,12
          float4 a = *(const float4*)(X + (size_t)(rowA + r) * D + k0 + c4);
          As[c4 + 0][r] = a.x; As[c4 + 1][r] = a.y;
          As[c4 + 2][r] = a.z; As[c4 + 3][r] = a.w;
          float4 w = *(const float4*)(W + (size_t)(rowB + r) * D + k0 + c4);
          Bs[c4 + 0][r] = w.x; Bs[c4 + 1][r] = w.y;
          Bs[c4 + 2][r] = w.z; Bs[c4 + 3][r] = w.w;
        }
        __syncthreads();
#pragma unroll
        for (int k = 0; k < BK; ++k) {
          float4 a0 = *(const float4*)&As[k][tm * 4];
          float4 a1 = *(const float4*)&As[k][64 + tm * 4];
          float4 b0 = *(const float4*)&Bs[k][tn * 4];
          float4 b1 = *(const float4*)&Bs[k][64 + tn * 4];
          float av[8] = {a0.x, a0.y, a0.z, a0.w, a1.x, a1.y, a1.z, a1.w};
          float bv[8] = {b0.x, b0.y, b0.z, b0.w, b1.x, b1.y, b1.z, b1.w};
#pragma unroll
          for (int i = 0; i < 8; ++i)
#pragma unroll
            for (int j = 0; j < 8; ++j)
              acc[i][j] = fmaf(av[i], bv[j], acc[i][j]);
        }
      }

      const int c0 = rowB + tn * 4;
      const int c1 = rowB + 64 + tn * 4;
      float4 bb0 = *(const float4*)(bias + c0);
      float4 bb1 = *(const float4*)(bias + c1);
      float bc[8] = {bb0.x, bb0.y, bb0.z, bb0.w, bb1.x, bb1.y, bb1.z, bb1.w};
#pragma unroll
      for (int i = 0; i < 8; ++i) {
        const int r = rowA + ((i < 4) ? (tm * 4 + i) : (64 + tm * 4 + (i - 4)));
        float4 v0, v1;
        v0.x = acc[i][0] + bc[0]; v0.y = acc[i][1] + bc[1];
        v0.z = acc[i][2] + bc[2]; v0.w = acc[i][3] + bc[3];
        v1.x = acc[i][4] + bc[4]; v1.y = acc[i][5] + bc[5];
        v1.z = acc[i][6] + bc[6]; v1.w = acc[i][7] + bc[7];
        *(float4*)(out + (size_t)r * Hh + c0) = v0;
        *(float4*)(out + (size_t)r * Hh + c1) = v1;
      }
      __syncthreads();  // barrier drain: all waves' stores at vmcnt(0)
      if (tid == 0)
        __hip_atomic_fetch_add(prog + bm, 1u, __ATOMIC_RELEASE,
                               __HIP_MEMORY_SCOPE_AGENT);
    }
    return;
  }

  // ---------------------------------------------------------- scan role ----
  if (tid >= 64) return;  // one wave
  __builtin_amdgcn_s_setprio(3);

  const int b = blockIdx.x;
  float* base = out + (size_t)b * (size_t)(T * Hh);
  const int h0 = tid * 4;
  const int h1 = 256 + tid * 4;

  float4 tav0 = *(const float4*)(ta + h0);
  float4 tav1 = *(const float4*)(ta + h1);
  float tac[8] = {tav0.x, tav0.y, tav0.z, tav0.w,
                  tav1.x, tav1.y, tav1.z, tav1.w};

#define WAIT_CHUNK(idx)                                                      \
  {                                                                          \
    unsigned* wp = prog + (idx);                                             \
    while (__hip_atomic_load(wp, __ATOMIC_RELAXED,                           \
                             __HIP_MEMORY_SCOPE_AGENT) < 4u) {}              \
    __builtin_amdgcn_fence(__ATOMIC_ACQUIRE, "agent");                       \
  }

  WAIT_CHUNK(b * 8);

  float4 pa[4], pb[4];
#pragma unroll
  for (int u = 0; u < 4; ++u) {
    pa[u] = *(const float4*)(base + (size_t)u * Hh + h0);
    pb[u] = *(const float4*)(base + (size_t)u * Hh + h1);
  }

  float xc[8], cc[8], mr[8];
  bool fire[8];
  {
    const float4 a = pa[0], bq = pb[0];
    xc[0] = a.x; xc[1] = a.y; xc[2] = a.z; xc[3] = a.w;
    xc[4] = bq.x; xc[5] = bq.y; xc[6] = bq.z; xc[7] = bq.w;
  }
#pragma unroll
  for (int i = 0; i < 8; ++i) { cc[i] = xc[i]; fire[i] = false; }

  // One scan step. u = t & 3 (compile-time), PF = prefetch t+4 allowed.
#define STEP(t, u, PF)                                                       \
  {                                                                          \
    if (PF) {                                                                \
      pa[u] = *(const float4*)(base + (size_t)((t) + 4) * Hh + h0);          \
      pb[u] = *(const float4*)(base + (size_t)((t) + 4) * Hh + h1);          \
    }                                                                        \
    _Pragma("unroll")                                                        \
    for (int i = 0; i < 8; ++i) mr[i] = fire[i] ? xc[i] : cc[i];             \
    float s_ = ((mr[0] + mr[1]) + (mr[2] + mr[3])) +                         \
               ((mr[4] + mr[5]) + (mr[6] + mr[7]));                          \
    float q_ = ((mr[0] * mr[0] + mr[1] * mr[1]) +                            \
                (mr[2] * mr[2] + mr[3] * mr[3])) +                           \
               ((mr[4] * mr[4] + mr[5] * mr[5]) +                            \
                (mr[6] * mr[6] + mr[7] * mr[7]));                            \
    { /* speculate next step; overlaps the reduce below */                   \
      const float4 na = pa[((u) + 1) & 3];                                   \
      const float4 nb = pb[((u) + 1) & 3];                                   \
      xc[0] = na.x; xc[1] = na.y; xc[2] = na.z; xc[3] = na.w;                \
      xc[4] = nb.x; xc[5] = nb.y; xc[6] = nb.z; xc[7] = nb.w;                \
      _Pragma("unroll")                                                      \
      for (int i = 0; i < 8; ++i) cc[i] = fmaf(ALPHA_F, mr[i], xc[i]);       \
    }                                                                        \
    s_ = dpp_reduce(s_);                                                     \
    q_ = dpp_reduce(q_);                                                     \
    float var_ = fmaxf((q_ - s_ * s_ * (1.0f / Hh)) * (1.0f / (Hh - 1)),     \
                       0.f);                                                 \
    float sdl_ = __builtin_amdgcn_sqrtf(var_); /* lane 63 valid */           \
    const float sd_ = __builtin_bit_cast(                                    \
        float,                                                               \
        __builtin_amdgcn_readlane(__builtin_bit_cast(int, sdl_), 63));       \
    float sp[8];                                                             \
    _Pragma("unroll")                                                        \
    for (int i = 0; i < 8; ++i) {                                            \
      fire[i] = mr[i] >= fmaf(0.1f, sd_, tac[i]);                            \
      sp[i] = fire[i] ? 1.f : 0.f;                                           \
    }                                                                        \
    *(float4*)(base + (size_t)(t) * Hh + h0) =                               \
        make_float4(sp[0], sp[1], sp[2], sp[3]);                             \
    *(float4*)(base + (size_t)(t) * Hh + h1) =                               \
        make_float4(sp[4], sp[5], sp[6], sp[7]);                             \
  }

  for (int ch = 0; ch < 8; ++ch) {
    const int cb = ch << 7;
    for (int it = 0; it < 31; ++it) {  // steps cb .. cb+123 (prefetch in-chunk)
      const int tb = cb + (it << 2);
      STEP(tb + 0, 0, true)
      STEP(tb + 1, 1, true)
      STEP(tb + 2, 2, true)
      STEP(tb + 3, 3, true)
    }
    const int tb = cb + 124;  // last 4 steps: prefetch crosses into chunk+1
    if (ch < 7) {
      WAIT_CHUNK(b * 8 + ch + 1);
      STEP(tb + 0, 0, true)
      STEP(tb + 1, 1, true)
      STEP(tb + 2, 2, true)
      STEP(tb + 3, 3, true)
    } else {
      STEP(tb + 0, 0, false)
      STEP(tb + 1, 1, false)
      STEP(tb + 2, 2, false)
      STEP(tb + 3, 3, false)
    }
  }
#undef STEP
#undef WAIT_CHUNK

  float mf[8];
#pragma unroll
  for (int i = 0; i < 8; ++i) mf[i] = fire[i] ? 0.f : mr[i];
  *(float4*)(memout + (size_t)b * Hh + h0) = make_float4(mf[0], mf[1], mf[2], mf[3]);
  *(float4*)(memout + (size_t)b * Hh + h1) = make_float4(mf[4], mf[5], mf[6], mf[7]);
}

// ------------------------------------------------- fallback (R2 proven) ----
__global__ __launch_bounds__(256) void gemm_kernel(
    const float* __restrict__ X, const float* __restrict__ W,
    const float* __restrict__ bias, float* __restrict__ out) {
  const int bn = blockIdx.x, bm = blockIdx.y;
  __shared__ float As[BK][BM + 4];
  __shared__ float Bs[BK][BN + 4];
  const int tid = threadIdx.x, tm = tid >> 4, tn = tid & 15;
  float acc[8][8];
#pragma unroll
  for (int i = 0; i < 8; ++i)
#pragma unroll
    for (int j = 0; j < 8; ++j) acc[i][j] = 0.f;
  const int rowA = bm * BM, rowB = bn * BN;
  for (int k0 = 0; k0 < D; k0 += BK) {
    __syncthreads();
#pragma unroll
    for (int i = 0; i < 2; ++i) {
      const int f = tid * 2 + i, r = f >> 2, c4 = (f & 3) << 2;
      float4 a = *(const float4*)(X + (size_t)(rowA + r) * D + k0 + c4);
      As[c4 + 0][r] = a.x; As[c4 + 1][r] = a.y;
      As[c4 + 2][r] = a.z; As[c4 + 3][r] = a.w;
      float4 w = *(const float4*)(W + (size_t)(rowB + r) * D + k0 + c4);
      Bs[c4 + 0][r] = w.x; Bs[c4 + 1][r] = w.y;
      Bs[c4 + 2][r] = w.z; Bs[c4 + 3][r] = w.w;
    }
    __syncthreads();
#pragma unroll
    for (int k = 0; k < BK; ++k) {
      float4 a0 = *(const float4*)&As[k][tm * 4];
      float4 a1 = *(const float4*)&As[k][64 + tm * 4];
      float4 b0 = *(const float4*)&Bs[k][tn * 4];
      float4 b1 = *(const float4*)&Bs[k][64 + tn * 4];
      float av[8] = {a0.x, a0.y, a0.z, a0.w, a1.x, a1.y, a1.z, a1.w};
      float bv[8] = {b0.x, b0.y, b0.z, b0.w, b1.x, b1.y, b1.z, b1.w};
#pragma unroll
      for (int i = 0; i < 8; ++i)
#pragma unroll
        for (int j = 0; j < 8; ++j)
          acc[i][j] = fmaf(av[i], bv[j], acc[i][j]);
    }
  }
  const int c0 = rowB + tn * 4, c1 = rowB + 64 + tn * 4;
  float4 bb0 = *(const float4*)(bias + c0);
  float4 bb1 = *(const float4*)(bias + c1);
  float bc[8] = {bb0.x, bb0.y, bb0.z, bb0.w, bb1.x, bb1.y, bb1.z, bb1.w};
#pragma unroll
  for (int i = 0; i < 8; ++i) {
    const int r = rowA + ((i < 4) ? (tm * 4 + i) : (64 + tm * 4 + (i - 4)));
    float4 v0, v1;
    v0.x = acc[i][0] + bc[0]; v0.y = acc[i][1] + bc[1];
    v0.z = acc[i][2] + bc[2]; v0.w = acc[i][3] + bc[3];
    v1.x = acc[i][4] + bc[4]; v1.y = acc[i][5] + bc[5];
    v1.z = acc[i][6] + bc[6]; v1.w = acc[i][7] + bc[7];
    *(float4*)(out + (size_t)r * Hh + c0) = v0;
    *(float4*)(out + (size_t)r * Hh + c1) = v1;
  }
}

__global__ __launch_bounds__(64) void scan_kernel(
    float* __restrict__ xs, const float* __restrict__ ta,
    float* __restrict__ memout) {
  const int b = blockIdx.x, lane = threadIdx.x;
  float* base = xs + (size_t)b * (size_t)(T * Hh);
  const int h0 = lane * 4, h1 = 256 + lane * 4;
  float4 tav0 = *(const float4*)(ta + h0);
  float4 tav1 = *(const float4*)(ta + h1);
  float tac[8] = {tav0.x, tav0.y, tav0.z, tav0.w,
                  tav1.x, tav1.y, tav1.z, tav1.w};
  float4 pa[4], pb[4];
#pragma unroll
  for (int u = 0; u < 4; ++u) {
    pa[u] = *(const float4*)(base + (size_t)u * Hh + h0);
    pb[u] = *(const float4*)(base + (size_t)u * Hh + h1);
  }
  float xc[8], cc[8], mr[8];
  bool fire[8];
  {
    const float4 a = pa[0], bq = pb[0];
    xc[0] = a.x; xc[1] = a.y; xc[2] = a.z; xc[3] = a.w;
    xc[4] = bq.x; xc[5] = bq.y; xc[6] = bq.z; xc[7] = bq.w;
  }
#pragma unroll
  for (int i = 0; i < 8; ++i) { cc[i] = xc[i]; fire[i] = false; }
  for (int t = 0; t < T; ++t) {
    const int u = t & 3;
    if (t + 4 < T) {
      pa[u] = *(const float4*)(base + (size_t)(t + 4) * Hh + h0);
      pb[u] = *(const float4*)(base + (size_t)(t + 4) * Hh + h1);
    }
#pragma unroll
    for (int i = 0; i < 8; ++i) mr[i] = fire[i] ? xc[i] : cc[i];
    float s = ((mr[0] + mr[1]) + (mr[2] + mr[3])) +
              ((mr[4] + mr[5]) + (mr[6] + mr[7]));
    float q = ((mr[0] * mr[0] + mr[1] * mr[1]) +
               (mr[2] * mr[2] + mr[3] * mr[3])) +
              ((mr[4] * mr[4] + mr[5] * mr[5]) +
               (mr[6] * mr[6] + mr[7] * mr[7]));
    {
      const float4 na = pa[(u + 1) & 3];
      const float4 nb = pb[(u + 1) & 3];
      xc[0] = na.x; xc[1] = na.y; xc[2] = na.z; xc[3] = na.w;
      xc[4] = nb.x; xc[5] = nb.y; xc[6] = nb.z; xc[7] = nb.w;
#pragma unroll
      for (int i = 0; i < 8; ++i) cc[i] = fmaf(ALPHA_F, mr[i], xc[i]);
    }
    s = dpp_reduce(s);
    q = dpp_reduce(q);
    float var = fmaxf((q - s * s * (1.0f / Hh)) * (1.0f / (Hh - 1)), 0.f);
    float sdl = __builtin_amdgcn_sqrtf(var);
    const float sd = __builtin_bit_cast(
        float, __builtin_amdgcn_readlane(__builtin_bit_cast(int, sdl), 63));
    float sp[8];
#pragma unroll
    for (int i = 0; i < 8; ++i) {
      fire[i] = mr[i] >= fmaf(0.1f, sd, tac[i]);
      sp[i] = fire[i] ? 1.f : 0.f;
    }
    *(float4*)(base + (size_t)t * Hh + h0) = make_float4(sp[0], sp[1], sp[2], sp[3]);
    *(float4*)(base + (size_t)t * Hh + h1) = make_float4(sp[4], sp[5], sp[6], sp[7]);
  }
  float mf[8];
#pragma unroll
  for (int i = 0; i < 8; ++i) mf[i] = fire[i] ? 0.f : mr[i];
  *(float4*)(memout + (size_t)b * Hh + h0) = make_float4(mf[0], mf[1], mf[2], mf[3]);
  *(float4*)(memout + (size_t)b * Hh + h1) = make_float4(mf[4], mf[5], mf[6], mf[7]);
}

// -------------------------------------------------------------- launch ----
extern "C" void kernel_launch(void* const* d_in, const int* in_sizes, int n_in,
                              void* d_out, int out_size, void* d_ws,
                              size_t ws_size, hipStream_t stream) {
  const float* x    = (const float*)d_in[0];
  const float* W    = (const float*)d_in[1];
  const float* bias = (const float*)d_in[2];
  const float* ta   = (const float*)d_in[3];

  float* out    = (float*)d_out;
  float* spikes = out;
  float* memout = out + (size_t)Bb * T * Hh;

  if (ws_size >= 257 * sizeof(unsigned)) {
    unsigned* ws = (unsigned*)d_ws;
    zero_ws_kernel<<<dim3(1), dim3(512), 0, stream>>>(ws);
    fused_kernel<<<dim3(NSCAN + NGEMM_BLOCKS), dim3(256), 0, stream>>>(
        x, W, bias, ta, spikes, memout, ws);
  } else {
    dim3 ggrid(Hh / BN, M / BM);
    gemm_kernel<<<ggrid, dim3(256), 0, stream>>>(x, W, bias, spikes);
    scan_kernel<<<dim3(Bb), dim3(64), 0, stream>>>(spikes, ta, memout);
  }
}

// Round 4
// 361.385 us; speedup vs baseline: 1.7249x; 1.1185x over previous
//
#include <hip/hip_runtime.h>

// SpikingNeuronLayer fused producer/consumer, R4:
//   grid = 256 blocks total -> 1 block/CU (round-robin placement), so the 32
//   scan blocks own their CUs and per-GEMM-tile wall time halves vs R3.
//   blocks 0..31   : scan role, one wave per batch row, prefetch depth 8,
//                    slimmed per-step VALU, spin-waits on per-chunk progress.
//   blocks 32..255 : persistent GEMM workers, claim 128x128 tiles chunk-major
//                    via atomic ticket, signal with agent-scope RELEASE add.
// xlin lands in d_out's spike region and is overwritten in place by the scan.

#define ALPHA_F 0.95122942450071402f  // float(exp(-1/20))

constexpr int Bb = 32, T = 1024, D = 512, Hh = 512;
constexpr int M = Bb * T;               // 32768
constexpr int NSCAN = 32;
constexpr int NGEMM_BLOCKS = 224;       // 32+224 = 256 = #CUs
constexpr int NTILES = (M / 128) * (Hh / 128);  // 1024

#define BM 128
#define BN 128
#define BK 16

// ------------------------------------------------------------ DPP reduce ----
template <int CTRL>
__device__ __forceinline__ float dpp_add(float v) {
  int s = __builtin_amdgcn_update_dpp(0, __builtin_bit_cast(int, v),
                                      CTRL, 0xF, 0xF, true);
  return v + __builtin_bit_cast(float, s);
}

// 64-lane sum; result valid in lane 63 only (caller readlanes).
__device__ __forceinline__ float dpp_reduce(float v) {
  v = dpp_add<0x111>(v);  // row_shr:1
  v = dpp_add<0x112>(v);  // row_shr:2
  v = dpp_add<0x114>(v);  // row_shr:4
  v = dpp_add<0x118>(v);  // row_shr:8
  v = dpp_add<0x142>(v);  // row_bcast15
  v = dpp_add<0x143>(v);  // row_bcast31 -> lane 63 = total
  return v;
}

// ------------------------------------------------------------- zero ws ----
__global__ void zero_ws_kernel(unsigned* ws) {
  if (threadIdx.x < 257) ws[threadIdx.x] = 0;  // prog[256] + ticket
}

// ------------------------------------------------------------ fused ----
__global__ __launch_bounds__(256) void fused_kernel(
    const float* __restrict__ X,     // [M, D]
    const float* __restrict__ W,     // [H, D]
    const float* __restrict__ bias,  // [H]
    const float* __restrict__ ta,    // [H]
    float* out,                      // [M, H]: xlin then spikes (in place)
    float* memout,                   // [B, H]
    unsigned* ws)                    // prog[256], ticket
{
  unsigned* prog = ws;
  unsigned* ticket = ws + 256;
  const int tid = threadIdx.x;

  if (blockIdx.x >= NSCAN) {
    // ------------------------------ GEMM role (persistent, ticketed) ------
    __shared__ float As[BK][BM + 4];
    __shared__ float Bs[BK][BN + 4];
    __shared__ unsigned s_g;
    const int tm = tid >> 4;
    const int tn = tid & 15;
    for (;;) {
      __syncthreads();  // protects s_g WAR + As/Bs across tiles
      if (tid == 0)
        s_g = __hip_atomic_fetch_add(ticket, 1u, __ATOMIC_RELAXED,
                                     __HIP_MEMORY_SCOPE_AGENT);
      __syncthreads();
      const unsigned g = s_g;
      if (g >= NTILES) break;  // uniform
      // chunk-major decode: g = c*128 + bt*4 + bn ; bm = bt*8 + c
      const int c  = (int)(g >> 7);
      const int bt = (int)((g & 127u) >> 2);
      const int bn = (int)(g & 3u);
      const int bm = bt * 8 + c;
      const int rowA = bm * BM;
      const int rowB = bn * BN;

      float acc[8][8];
#pragma unroll
      for (int i = 0; i < 8; ++i)
#pragma unroll
        for (int j = 0; j < 8; ++j) acc[i][j] = 0.f;

      for (int k0 = 0; k0 < D; k0 += BK) {
        __syncthreads();
#pragma unroll
        for (int i = 0; i < 2; ++i) {
          const int f = tid * 2 + i;    // 0..511
          const int r = f >> 2;         // 0..127
          const int c4 = (f & 3) << 2;  // 0,4,8,12
          float4 a = *(const float4*)(X + (size_t)(rowA + r) * D + k0 + c4);
          As[c4 + 0][r] = a.x; As[c4 + 1][r] = a.y;
          As[c4 + 2][r] = a.z; As[c4 + 3][r] = a.w;
          float4 w = *(const float4*)(W + (size_t)(rowB + r) * D + k0 + c4);
          Bs[c4 + 0][r] = w.x; Bs[c4 + 1][r] = w.y;
          Bs[c4 + 2][r] = w.z; Bs[c4 + 3][r] = w.w;
        }
        __syncthreads();
#pragma unroll
        for (int k = 0; k < BK; ++k) {
          float4 a0 = *(const float4*)&As[k][tm * 4];
          float4 a1 = *(const float4*)&As[k][64 + tm * 4];
          float4 b0 = *(const float4*)&Bs[k][tn * 4];
          float4 b1 = *(const float4*)&Bs[k][64 + tn * 4];
          float av[8] = {a0.x, a0.y, a0.z, a0.w, a1.x, a1.y, a1.z, a1.w};
          float bv[8] = {b0.x, b0.y, b0.z, b0.w, b1.x, b1.y, b1.z, b1.w};
#pragma unroll
          for (int i = 0; i < 8; ++i)
#pragma unroll
            for (int j = 0; j < 8; ++j)
              acc[i][j] = fmaf(av[i], bv[j], acc[i][j]);
        }
      }

      const int c0 = rowB + tn * 4;
      const int c1 = rowB + 64 + tn * 4;
      float4 bb0 = *(const float4*)(bias + c0);
      float4 bb1 = *(const float4*)(bias + c1);
      float bc[8] = {bb0.x, bb0.y, bb0.z, bb0.w, bb1.x, bb1.y, bb1.z, bb1.w};
#pragma unroll
      for (int i = 0; i < 8; ++i) {
        const int r = rowA + ((i < 4) ? (tm * 4 + i) : (64 + tm * 4 + (i - 4)));
        float4 v0, v1;
        v0.x = acc[i][0] + bc[0]; v0.y = acc[i][1] + bc[1];
        v0.z = acc[i][2] + bc[2]; v0.w = acc[i][3] + bc[3];
        v1.x = acc[i][4] + bc[4]; v1.y = acc[i][5] + bc[5];
        v1.z = acc[i][6] + bc[6]; v1.w = acc[i][7] + bc[7];
        *(float4*)(out + (size_t)r * Hh + c0) = v0;
        *(float4*)(out + (size_t)r * Hh + c1) = v1;
      }
      __syncthreads();  // barrier drain: all waves' stores at vmcnt(0)
      if (tid == 0)
        __hip_atomic_fetch_add(prog + bm, 1u, __ATOMIC_RELEASE,
                               __HIP_MEMORY_SCOPE_AGENT);
    }
    return;
  }

  // ---------------------------------------------------------- scan role ----
  if (tid >= 64) return;  // one wave
  __builtin_amdgcn_s_setprio(3);

  const int b = blockIdx.x;
  float* base = out + (size_t)b * (size_t)(T * Hh);
  const int h0 = tid * 4;
  const int h1 = 256 + tid * 4;

  float4 tav0 = *(const float4*)(ta + h0);
  float4 tav1 = *(const float4*)(ta + h1);
  float tac[8] = {tav0.x, tav0.y, tav0.z, tav0.w,
                  tav1.x, tav1.y, tav1.z, tav1.w};

#define WAIT_CHUNK(idx)                                                      \
  {                                                                          \
    unsigned* wp = prog + (idx);                                             \
    while (__hip_atomic_load(wp, __ATOMIC_RELAXED,                           \
                             __HIP_MEMORY_SCOPE_AGENT) < 4u) {               \
      __builtin_amdgcn_s_sleep(2);                                           \
    }                                                                        \
    __builtin_amdgcn_fence(__ATOMIC_ACQUIRE, "agent");                       \
  }

  WAIT_CHUNK(b * 8);

  // prefetch depth 8: slot u holds timestep congruent to u (mod 8)
  float4 pa[8], pb[8];
#pragma unroll
  for (int u = 0; u < 8; ++u) {
    pa[u] = *(const float4*)(base + (size_t)u * Hh + h0);
    pb[u] = *(const float4*)(base + (size_t)u * Hh + h1);
  }

  float cc[8], mr[8];
  bool fire[8];
#pragma unroll
  for (int i = 0; i < 8; ++i) fire[i] = false;
  // cc for t=0 is x_0 (mem starts at 0): cc = pa[0]/pb[0] values.
  cc[0] = pa[0].x; cc[1] = pa[0].y; cc[2] = pa[0].z; cc[3] = pa[0].w;
  cc[4] = pb[0].x; cc[5] = pb[0].y; cc[6] = pb[0].z; cc[7] = pb[0].w;

  // One scan step; u = t & 7 compile-time; n = (u+1)&7; PF: prefetch t+8.
  // Order: select (reads pa[u]) -> prefetch pa[u]<-t+8 (issue early) ->
  // trees + speculative cc (reads pa[n], still intact) -> reduce -> spike.
#define STEP(t, u, PF)                                                       \
  {                                                                          \
    constexpr int n_ = ((u) + 1) & 7;                                        \
    const float xu_[8] = {pa[u].x, pa[u].y, pa[u].z, pa[u].w,                \
                          pb[u].x, pb[u].y, pb[u].z, pb[u].w};               \
    _Pragma("unroll")                                                        \
    for (int i = 0; i < 8; ++i) mr[i] = fire[i] ? xu_[i] : cc[i];            \
    if (PF) {                                                                \
      pa[u] = *(const float4*)(base + (size_t)((t) + 8) * Hh + h0);          \
      pb[u] = *(const float4*)(base + (size_t)((t) + 8) * Hh + h1);          \
    }                                                                        \
    float s_ = ((mr[0] + mr[1]) + (mr[2] + mr[3])) +                         \
               ((mr[4] + mr[5]) + (mr[6] + mr[7]));                          \
    float q_ = mr[0] * mr[0];                                                \
    q_ = fmaf(mr[1], mr[1], q_); q_ = fmaf(mr[2], mr[2], q_);                \
    q_ = fmaf(mr[3], mr[3], q_); q_ = fmaf(mr[4], mr[4], q_);                \
    q_ = fmaf(mr[5], mr[5], q_); q_ = fmaf(mr[6], mr[6], q_);                \
    q_ = fmaf(mr[7], mr[7], q_);                                             \
    { /* speculative next step from pa[n_] (loaded t-7, intact) */           \
      const float xn_[8] = {pa[n_].x, pa[n_].y, pa[n_].z, pa[n_].w,          \
                            pb[n_].x, pb[n_].y, pb[n_].z, pb[n_].w};         \
      _Pragma("unroll")                                                      \
      for (int i = 0; i < 8; ++i) cc[i] = fmaf(ALPHA_F, mr[i], xn_[i]);      \
    }                                                                        \
    s_ = dpp_reduce(s_);                                                     \
    q_ = dpp_reduce(q_);                                                     \
    float var_ = fmaf(s_ * s_, -(1.0f / Hh), q_) * (1.0f / (Hh - 1));        \
    var_ = fmaxf(var_, 0.f);                                                 \
    float sdl_ = __builtin_amdgcn_sqrtf(var_); /* lane 63 valid */           \
    const float sd_ = __builtin_bit_cast(                                    \
        float,                                                               \
        __builtin_amdgcn_readlane(__builtin_bit_cast(int, sdl_), 63));       \
    float sp[8];                                                             \
    _Pragma("unroll")                                                        \
    for (int i = 0; i < 8; ++i) {                                            \
      fire[i] = mr[i] >= fmaf(0.1f, sd_, tac[i]);                            \
      sp[i] = fire[i] ? 1.f : 0.f;                                           \
    }                                                                        \
    *(float4*)(base + (size_t)(t) * Hh + h0) =                               \
        make_float4(sp[0], sp[1], sp[2], sp[3]);                             \
    *(float4*)(base + (size_t)(t) * Hh + h1) =                               \
        make_float4(sp[4], sp[5], sp[6], sp[7]);                             \
  }

#define STEP8(tb, PF)                                                        \
  STEP((tb) + 0, 0, PF) STEP((tb) + 1, 1, PF) STEP((tb) + 2, 2, PF)          \
  STEP((tb) + 3, 3, PF) STEP((tb) + 4, 4, PF) STEP((tb) + 5, 5, PF)          \
  STEP((tb) + 6, 6, PF) STEP((tb) + 7, 7, PF)

  for (int ch = 0; ch < 8; ++ch) {
    const int cb = ch << 7;
    for (int it = 0; it < 15; ++it) {  // steps cb..cb+119: prefetch in-chunk
      STEP8(cb + (it << 3), true)
    }
    // last 8 steps of chunk: prefetch crosses into chunk+1
    if (ch < 7) {
      WAIT_CHUNK(b * 8 + ch + 1);
      STEP8(cb + 120, true)
    } else {
      STEP8(cb + 120, false)
    }
  }
#undef STEP8
#undef STEP
#undef WAIT_CHUNK

  float mf[8];
#pragma unroll
  for (int i = 0; i < 8; ++i) mf[i] = fire[i] ? 0.f : mr[i];
  *(float4*)(memout + (size_t)b * Hh + h0) = make_float4(mf[0], mf[1], mf[2], mf[3]);
  *(float4*)(memout + (size_t)b * Hh + h1) = make_float4(mf[4], mf[5], mf[6], mf[7]);
}

// ------------------------------------------------- fallback (R2 proven) ----
__global__ __launch_bounds__(256) void gemm_kernel(
    const float* __restrict__ X, const float* __restrict__ W,
    const float* __restrict__ bias, float* __restrict__ out) {
  const int bn = blockIdx.x, bm = blockIdx.y;
  __shared__ float As[BK][BM + 4];
  __shared__ float Bs[BK][BN + 4];
  const int tid = threadIdx.x, tm = tid >> 4, tn = tid & 15;
  float acc[8][8];
#pragma unroll
  for (int i = 0; i < 8; ++i)
#pragma unroll
    for (int j = 0; j < 8; ++j) acc[i][j] = 0.f;
  const int rowA = bm * BM, rowB = bn * BN;
  for (int k0 = 0; k0 < D; k0 += BK) {
    __syncthreads();
#pragma unroll
    for (int i = 0; i < 2; ++i) {
      const int f = tid * 2 + i, r = f >> 2, c4 = (f & 3) << 2;
      float4 a = *(const float4*)(X + (size_t)(rowA + r) * D + k0 + c4);
      As[c4 + 0][r] = a.x; As[c4 + 1][r] = a.y;
      As[c4 + 2][r] = a.z; As[c4 + 3][r] = a.w;
      float4 w = *(const float4*)(W + (size_t)(rowB + r) * D + k0 + c4);
      Bs[c4 + 0][r] = w.x; Bs[c4 + 1][r] = w.y;
      Bs[c4 + 2][r] = w.z; Bs[c4 + 3][r] = w.w;
    }
    __syncthreads();
#pragma unroll
    for (int k = 0; k < BK; ++k) {
      float4 a0 = *(const float4*)&As[k][tm * 4];
      float4 a1 = *(const float4*)&As[k][64 + tm * 4];
      float4 b0 = *(const float4*)&Bs[k][tn * 4];
      float4 b1 = *(const float4*)&Bs[k][64 + tn * 4];
      float av[8] = {a0.x, a0.y, a0.z, a0.w, a1.x, a1.y, a1.z, a1.w};
      float bv[8] = {b0.x, b0.y, b0.z, b0.w, b1.x, b1.y, b1.z, b1.w};
#pragma unroll
      for (int i = 0; i < 8; ++i)
#pragma unroll
        for (int j = 0; j < 8; ++j)
          acc[i][j] = fmaf(av[i], bv[j], acc[i][j]);
    }
  }
  const int c0 = rowB + tn * 4, c1 = rowB + 64 + tn * 4;
  float4 bb0 = *(const float4*)(bias + c0);
  float4 bb1 = *(const float4*)(bias + c1);
  float bc[8] = {bb0.x, bb0.y, bb0.z, bb0.w, bb1.x, bb1.y, bb1.z, bb1.w};
#pragma unroll
  for (int i = 0; i < 8; ++i) {
    const int r = rowA + ((i < 4) ? (tm * 4 + i) : (64 + tm * 4 + (i - 4)));
    float4 v0, v1;
    v0.x = acc[i][0] + bc[0]; v0.y = acc[i][1] + bc[1];
    v0.z = acc[i][2] + bc[2]; v0.w = acc[i][3] + bc[3];
    v1.x = acc[i][4] + bc[4]; v1.y = acc[i][5] + bc[5];
    v1.z = acc[i][6] + bc[6]; v1.w = acc[i][7] + bc[7];
    *(float4*)(out + (size_t)r * Hh + c0) = v0;
    *(float4*)(out + (size_t)r * Hh + c1) = v1;
  }
}

__global__ __launch_bounds__(64) void scan_kernel(
    float* __restrict__ xs, const float* __restrict__ ta,
    float* __restrict__ memout) {
  const int b = blockIdx.x, lane = threadIdx.x;
  float* base = xs + (size_t)b * (size_t)(T * Hh);
  const int h0 = lane * 4, h1 = 256 + lane * 4;
  float4 tav0 = *(const float4*)(ta + h0);
  float4 tav1 = *(const float4*)(ta + h1);
  float tac[8] = {tav0.x, tav0.y, tav0.z, tav0.w,
                  tav1.x, tav1.y, tav1.z, tav1.w};
  float4 pa[4], pb[4];
#pragma unroll
  for (int u = 0; u < 4; ++u) {
    pa[u] = *(const float4*)(base + (size_t)u * Hh + h0);
    pb[u] = *(const float4*)(base + (size_t)u * Hh + h1);
  }
  float xc[8], cc[8], mr[8];
  bool fire[8];
  {
    const float4 a = pa[0], bq = pb[0];
    xc[0] = a.x; xc[1] = a.y; xc[2] = a.z; xc[3] = a.w;
    xc[4] = bq.x; xc[5] = bq.y; xc[6] = bq.z; xc[7] = bq.w;
  }
#pragma unroll
  for (int i = 0; i < 8; ++i) { cc[i] = xc[i]; fire[i] = false; }
  for (int t = 0; t < T; ++t) {
    const int u = t & 3;
    if (t + 4 < T) {
      pa[u] = *(const float4*)(base + (size_t)(t + 4) * Hh + h0);
      pb[u] = *(const float4*)(base + (size_t)(t + 4) * Hh + h1);
    }
#pragma unroll
    for (int i = 0; i < 8; ++i) mr[i] = fire[i] ? xc[i] : cc[i];
    float s = ((mr[0] + mr[1]) + (mr[2] + mr[3])) +
              ((mr[4] + mr[5]) + (mr[6] + mr[7]));
    float q = ((mr[0] * mr[0] + mr[1] * mr[1]) +
               (mr[2] * mr[2] + mr[3] * mr[3])) +
              ((mr[4] * mr[4] + mr[5] * mr[5]) +
               (mr[6] * mr[6] + mr[7] * mr[7]));
    {
      const float4 na = pa[(u + 1) & 3];
      const float4 nb = pb[(u + 1) & 3];
      xc[0] = na.x; xc[1] = na.y; xc[2] = na.z; xc[3] = na.w;
      xc[4] = nb.x; xc[5] = nb.y; xc[6] = nb.z; xc[7] = nb.w;
#pragma unroll
      for (int i = 0; i < 8; ++i) cc[i] = fmaf(ALPHA_F, mr[i], xc[i]);
    }
    s = dpp_reduce(s);
    q = dpp_reduce(q);
    float var = fmaxf((q - s * s * (1.0f / Hh)) * (1.0f / (Hh - 1)), 0.f);
    float sdl = __builtin_amdgcn_sqrtf(var);
    const float sd = __builtin_bit_cast(
        float, __builtin_amdgcn_readlane(__builtin_bit_cast(int, sdl), 63));
    float sp[8];
#pragma unroll
    for (int i = 0; i < 8; ++i) {
      fire[i] = mr[i] >= fmaf(0.1f, sd, tac[i]);
      sp[i] = fire[i] ? 1.f : 0.f;
    }
    *(float4*)(base + (size_t)t * Hh + h0) = make_float4(sp[0], sp[1], sp[2], sp[3]);
    *(float4*)(base + (size_t)t * Hh + h1) = make_float4(sp[4], sp[5], sp[6], sp[7]);
  }
  float mf[8];
#pragma unroll
  for (int i = 0; i < 8; ++i) mf[i] = fire[i] ? 0.f : mr[i];
  *(float4*)(memout + (size_t)b * Hh + h0) = make_float4(mf[0], mf[1], mf[2], mf[3]);
  *(float4*)(memout + (size_t)b * Hh + h1) = make_float4(mf[4], mf[5], mf[6], mf[7]);
}

// -------------------------------------------------------------- launch ----
extern "C" void kernel_launch(void* const* d_in, const int* in_sizes, int n_in,
                              void* d_out, int out_size, void* d_ws,
                              size_t ws_size, hipStream_t stream) {
  const float* x    = (const float*)d_in[0];
  const float* W    = (const float*)d_in[1];
  const float* bias = (const float*)d_in[2];
  const float* ta   = (const float*)d_in[3];

  float* out    = (float*)d_out;
  float* spikes = out;
  float* memout = out + (size_t)Bb * T * Hh;

  if (ws_size >= 257 * sizeof(unsigned)) {
    unsigned* ws = (unsigned*)d_ws;
    zero_ws_kernel<<<dim3(1), dim3(512), 0, stream>>>(ws);
    fused_kernel<<<dim3(NSCAN + NGEMM_BLOCKS), dim3(256), 0, stream>>>(
        x, W, bias, ta, spikes, memout, ws);
  } else {
    dim3 ggrid(Hh / BN, M / BM);
    gemm_kernel<<<ggrid, dim3(256), 0, stream>>>(x, W, bias, spikes);
    scan_kernel<<<dim3(Bb), dim3(64), 0, stream>>>(spikes, ta, memout);
  }
}